// Round 4
// baseline (9428.827 us; speedup 1.0000x reference)
//
#include <hip/hip_runtime.h>
#include <math.h>

#define S_LEN 256
#define BATCH 64
#define NIN   1024
#define NH    2048
#define SCAN_BLOCKS  128   // 16 cols each, col-swizzled so each XCD owns 256 contiguous cols
#define SCAN_THREADS 512   // 8 waves, K-split 8x256

typedef short s16x8 __attribute__((ext_vector_type(8)));
typedef float f32x4 __attribute__((ext_vector_type(4)));
typedef float f32x2 __attribute__((ext_vector_type(2)));
typedef unsigned short u16x4 __attribute__((ext_vector_type(4)));

__device__ inline unsigned short f2bf(float f){
  unsigned int u = __float_as_uint(f);
  u += 0x7fffu + ((u >> 16) & 1u);      // round-to-nearest-even
  return (unsigned short)(u >> 16);
}

// packed fp32->bf16 RNE (2 elems / instr); dst lo = bf16(x), dst hi = bf16(y)
__device__ inline unsigned int pk2(float x, float y){
  unsigned int r;
  asm("v_cvt_pk_bf16_f32 %0, %1, %2" : "=v"(r) : "v"(x), "v"(y));
  return r;
}

__global__ void k_cast_bf16(const float* __restrict__ in,
                            unsigned short* __restrict__ out, int n4){
  int i = blockIdx.x * blockDim.x + threadIdx.x;
  if (i >= n4) return;
  float4 v = ((const float4*)in)[i];
  u16x4 o;
  o.x = f2bf(v.x); o.y = f2bf(v.y); o.z = f2bf(v.z); o.w = f2bf(v.w);
  ((u16x4*)out)[i] = o;
}

// h0 [64][2048] fp32 -> hbuf slot0, block-major [128 p][64 row][16 col] bf16
__global__ void k_cast_h0(const float* __restrict__ h0,
                          unsigned short* __restrict__ hb){
  int p = blockIdx.x;                       // 128 blocks
  int row = threadIdx.x >> 2;               // 256 threads: 64 rows x 4 col-groups
  int c4  = (threadIdx.x & 3) * 4;
  f32x4 v = *(const f32x4*)(h0 + (size_t)row * NH + p * 16 + c4);
  u16x4 o;
  o.x = f2bf(v[0]); o.y = f2bf(v[1]); o.z = f2bf(v[2]); o.w = f2bf(v[3]);
  *(u16x4*)(hb + ((size_t)p * 64 + row) * 16 + c4) = o;
}

// out[n][k] = bf16(in[k][n]);  K,N multiples of 32
__global__ void k_transpose_bf16(const float* __restrict__ in,
                                 unsigned short* __restrict__ out, int K, int N){
  __shared__ unsigned short tile[32][33];
  int n0 = blockIdx.x * 32, k0 = blockIdx.y * 32;
  int tx = threadIdx.x, ty = threadIdx.y;   // 32 x 8
  #pragma unroll
  for (int i = 0; i < 4; ++i)
    tile[ty + i*8][tx] = f2bf(in[(size_t)(k0 + ty + i*8) * N + n0 + tx]);
  __syncthreads();
  #pragma unroll
  for (int i = 0; i < 4; ++i)
    out[(size_t)(n0 + ty + i*8) * K + k0 + tx] = tile[tx][ty + i*8];
}

// base = x @ Wx + bx + bh  (fp32 into d_out)
__global__ __launch_bounds__(256) void k_xproj(
    const unsigned short* __restrict__ xbf,   // [16384][1024] bf16
    const unsigned short* __restrict__ wxt,   // [2048][1024]  bf16 (Wx^T)
    const float* __restrict__ bx,
    const float* __restrict__ bh,
    float* __restrict__ out)                  // [16384][2048] fp32
{
  int wave = threadIdx.x >> 6, lane = threadIdx.x & 63;
  int q = lane >> 4, r = lane & 15;
  int m0 = blockIdx.y * 64 + wave * 16;
  int n0 = blockIdx.x * 64;

  const unsigned short* arow = xbf + (size_t)(m0 + r) * NIN + q * 8;
  const unsigned short* brow = wxt + (size_t)(n0 + r) * NIN + q * 8;

  f32x4 acc[4] = {};
  #pragma unroll 2
  for (int kk = 0; kk < NIN; kk += 32){
    s16x8 a = *(const s16x8*)(arow + kk);
    #pragma unroll
    for (int j = 0; j < 4; ++j){
      s16x8 b = *(const s16x8*)(brow + (size_t)j * 16 * NIN + kk);
      acc[j] = __builtin_amdgcn_mfma_f32_16x16x32_bf16(a, b, acc[j], 0, 0, 0);
    }
  }
  #pragma unroll
  for (int j = 0; j < 4; ++j){
    int col = n0 + j * 16 + r;
    float bias = bx[col] + bh[col];
    #pragma unroll
    for (int i = 0; i < 4; ++i){
      int row = m0 + q * 4 + i;
      out[(size_t)row * NH + col] = acc[j][i] + bias;
    }
  }
}

// Persistent weight-stationary scan, v5.
// Law from v2/v4 counters: step_time = EA(L2-miss) bytes / ~183 GB/s. So:
//  - h exchange: bf16 ping-pong (halves h bytes vs fp32), BLOCK-MAJOR layout
//    [2][128 p][64 row][16 col] so each producer's 2 KB slice is line-perfect
//    (write amp 1.0) via sc0/sc1 atomic stores.
//  - out stores: PLAIN cached write-back (consumers never read out; dirty
//    lines evict as full 64B lines off the critical window; kernel-end flush
//    publishes them). Kills the ~2x write-through amplification.
//  - base reads: plain cached loads (addresses written only by k_xproj before
//    the scan, then by this block itself with PLAIN stores -> L1/L2 stay
//    coherent for the only reader).
//  - 128 blocks (vs 64): 2x outstanding-miss concurrency to push effective EA
//    bandwidth up; h-refill EA traffic scales with #XCDs (8), not #blocks.
//  - col-swizzle cp=(b&7)*16+(b>>3): XCD x owns cols [256x,256x+256) => base
//    reads / out writes are XCD-contiguous 1KB-per-row chunks.
// Sync skeleton proven in v2 (its cost is ~0 per the traffic fit): wave0 polls
// flags, one agent acquire fence (inv), syncthreads; epilogue hn stores are
// sc0/sc1 drained by syncthreads' vmcnt(0) before the relaxed flag store.
__global__ __launch_bounds__(SCAN_THREADS, 2) void k_scan_persist(
    unsigned short* __restrict__ hbuf,      // 2 x [128][64][16] bf16 ping-pong (slot0 = h0)
    const unsigned short* __restrict__ wht, // [2048][2048] bf16 (Wh^T)
    float* __restrict__ out,                // [256][64][2048] fp32 (base in, tanh out)
    unsigned int* __restrict__ flags)       // 128 flags, stride 4 uints (16B), zeroed
{
  __shared__ float red[8][BATCH][20];       // 16 cols + 4 pad (2-way max = free)

  const int tid = threadIdx.x;
  const int wave = tid >> 6, lane = tid & 63;
  const int q = lane >> 4, r = lane & 15;
  const int cp = ((blockIdx.x & 7) << 4) | (blockIdx.x >> 3);  // col-block 0..127
  const int n0 = cp * 16;
  const int kbase = wave * 256;

  // ---- preload Wh^T slice into registers (once): 16 cols x 8 k-tiles ----
  s16x8 breg[8];
  #pragma unroll
  for (int kk = 0; kk < 8; ++kk)
    breg[kk] = *(const s16x8*)(wht + (size_t)(n0 + r) * NH + kbase + kk*32 + q*8);

  const int crow = tid >> 3;        // 0..63  (epilogue mapping)
  const int ccol = (tid & 7) * 2;   // 0,2,..,14
  const size_t g = (size_t)crow * NH + n0 + ccol;          // fp32 out offset
  const size_t hg = ((size_t)cp * 64 + crow) * 16 + ccol;  // bf16 hbuf offset

  // base for t=0: plain cached load (k_xproj flushed at its kernel boundary)
  f32x2 base = *(const f32x2*)(out + g);

  for (int t = 0; t < S_LEN; ++t){
    const unsigned short* hc = hbuf + (size_t)(t & 1) * 128 * 64 * 16;
    unsigned short* hn       = hbuf + (size_t)((t + 1) & 1) * 128 * 64 * 16;
    float* outT = out + (size_t)t * BATCH * NH;

    // ---- wait: all 128 producers finished step t-1 ----
    if (t > 0){
      if (wave == 0){
        const unsigned int target = (unsigned int)t;
        const unsigned int* f0 = flags + ((unsigned)lane << 2);
        const unsigned int* f1 = flags + ((unsigned)(lane + 64) << 2);
        for (;;){
          unsigned int a = __hip_atomic_load(f0, __ATOMIC_RELAXED, __HIP_MEMORY_SCOPE_AGENT);
          unsigned int b = __hip_atomic_load(f1, __ATOMIC_RELAXED, __HIP_MEMORY_SCOPE_AGENT);
          if (__all((int)(a >= target && b >= target))) break;
        }
        // invalidate stale ping-pong h lines cached 2 steps ago
        __builtin_amdgcn_fence(__ATOMIC_ACQUIRE, "agent");
      }
      __syncthreads();              // (C) release waves 1..7; orders h loads
    }

    // ---- partial GEMM over this wave's k-range (K=256) ----
    // logical k-col c = kbase + kk*32 + q*8  ->  producer p = c>>4, off = c&15
    f32x4 acc[4] = {};
    #pragma unroll 4
    for (int kk = 0; kk < 8; ++kk){
      const int p   = 16 * wave + 2 * kk + (q >> 1);
      const int off = (q & 1) * 8;
      const unsigned short* hp = hc + ((size_t)p * 64 + r) * 16 + off;
      s16x8 a[4];
      #pragma unroll
      for (int m = 0; m < 4; ++m)
        a[m] = *(const s16x8*)(hp + (size_t)m * 16 * 16);
      #pragma unroll
      for (int m = 0; m < 4; ++m)
        acc[m] = __builtin_amdgcn_mfma_f32_16x16x32_bf16(a[m], breg[kk], acc[m], 0, 0, 0);
    }

    // ---- single-pass K-reduce staging: all 8 waves write partials ----
    #pragma unroll
    for (int m = 0; m < 4; ++m)
      #pragma unroll
      for (int i = 0; i < 4; ++i)
        red[wave][m*16 + q*4 + i][r] = acc[m][i];
    __syncthreads();                // (A)

    // ---- epilogue: all 512 threads, 2 elems each ----
    {
      float s0 = 0.f, s1 = 0.f;
      #pragma unroll
      for (int w = 0; w < 8; ++w){
        s0 += red[w][crow][ccol];
        s1 += red[w][crow][ccol + 1];
      }
      float tv0 = tanhf(base[0] + s0);
      float tv1 = tanhf(base[1] + s1);

      f32x2 ov; ov[0] = tv0; ov[1] = tv1;
      *(f32x2*)(outT + g) = ov;     // PLAIN cached store (write-back, full lines)

      // hn: sc0/sc1 write-through, block-major slice (line-perfect)
      __hip_atomic_store((unsigned int*)(hn + hg), pk2(tv0, tv1),
                         __ATOMIC_RELAXED, __HIP_MEMORY_SCOPE_AGENT);
    }

    __syncthreads();                // (B) vmcnt(0) drain => hn stores at MALL
    if (tid == 0)
      __hip_atomic_store(flags + ((unsigned)cp << 2), (unsigned int)(t + 1),
                         __ATOMIC_RELAXED, __HIP_MEMORY_SCOPE_AGENT);

    // prefetch next step's base (plain; written only by k_xproj / this block)
    if (t + 1 < S_LEN)
      base = *(const f32x2*)(out + (size_t)(t + 1) * BATCH * NH + g);
  }
}

extern "C" void kernel_launch(void* const* d_in, const int* in_sizes, int n_in,
                              void* d_out, int out_size, void* d_ws, size_t ws_size,
                              hipStream_t stream){
  const float* x  = (const float*)d_in[0];
  const float* h0 = (const float*)d_in[1];
  const float* Wx = (const float*)d_in[2];
  const float* bx = (const float*)d_in[3];
  const float* Wh = (const float*)d_in[4];
  const float* bh = (const float*)d_in[5];
  float* out = (float*)d_out;

  char* ws = (char*)d_ws;
  unsigned short* xbf  = (unsigned short*)(ws);                               // 33,554,432 B
  unsigned short* wxt  = (unsigned short*)(ws + 33554432);                    //  4,194,304 B
  unsigned short* wht  = (unsigned short*)(ws + 33554432 + 4194304);          //  8,388,608 B
  unsigned short* hbuf = (unsigned short*)(ws + 33554432 + 4194304 + 8388608);//    524,288 B
  // flag array (128 x 16B) aliases xbf[0..1024) — xbf is dead after k_xproj
  unsigned int* flags = (unsigned int*)ws;

  // 1) casts
  k_cast_bf16<<<dim3(16384), 256, 0, stream>>>(x, xbf, 4194304);
  k_cast_h0<<<dim3(128), 256, 0, stream>>>(h0, hbuf);
  // 2) weight transposes to [n][k] bf16
  k_transpose_bf16<<<dim3(NH/32, NIN/32), dim3(32, 8), 0, stream>>>(Wx, wxt, NIN, NH);
  k_transpose_bf16<<<dim3(NH/32, NH/32),  dim3(32, 8), 0, stream>>>(Wh, wht, NH, NH);
  // 3) base = x@Wx + bx + bh -> d_out
  k_xproj<<<dim3(NH/64, (S_LEN*BATCH)/64), 256, 0, stream>>>(xbf, wxt, bx, bh, out);
  // 4) zero flag array (xbf dead now), then persistent scan
  hipMemsetAsync(flags, 0, 2048, stream);
  {
    void* args[] = { (void*)&hbuf, (void*)&wht, (void*)&out, (void*)&flags };
    hipLaunchCooperativeKernel((const void*)k_scan_persist,
                               dim3(SCAN_BLOCKS), dim3(SCAN_THREADS), args, 0, stream);
  }
  // 5) hn = outputs[255]
  hipMemcpyAsync(out + (size_t)S_LEN * BATCH * NH,
                 out + (size_t)(S_LEN - 1) * BATCH * NH,
                 sizeof(float) * (size_t)BATCH * NH,
                 hipMemcpyDeviceToDevice, stream);
}

// Round 5
// 4223.052 us; speedup vs baseline: 2.2327x; 2.2327x over previous
//
#include <hip/hip_runtime.h>
#include <math.h>

#define S_LEN 256
#define BATCH 64
#define NIN   1024
#define NH    2048
#define SCAN_BLOCKS  64    // 32 cols each
#define SCAN_THREADS 512   // 8 waves, K-split 8x256

typedef short s16x8 __attribute__((ext_vector_type(8)));
typedef float f32x4 __attribute__((ext_vector_type(4)));
typedef unsigned short u16x4 __attribute__((ext_vector_type(4)));

__device__ inline unsigned short f2bf(float f){
  unsigned int u = __float_as_uint(f);
  u += 0x7fffu + ((u >> 16) & 1u);      // round-to-nearest-even
  return (unsigned short)(u >> 16);
}

__global__ void k_cast_bf16(const float* __restrict__ in,
                            unsigned short* __restrict__ out, int n4){
  int i = blockIdx.x * blockDim.x + threadIdx.x;
  if (i >= n4) return;
  float4 v = ((const float4*)in)[i];
  u16x4 o;
  o.x = f2bf(v.x); o.y = f2bf(v.y); o.z = f2bf(v.z); o.w = f2bf(v.w);
  ((u16x4*)out)[i] = o;
}

// out[n][k] = bf16(in[k][n]);  K,N multiples of 32
__global__ void k_transpose_bf16(const float* __restrict__ in,
                                 unsigned short* __restrict__ out, int K, int N){
  __shared__ unsigned short tile[32][33];
  int n0 = blockIdx.x * 32, k0 = blockIdx.y * 32;
  int tx = threadIdx.x, ty = threadIdx.y;   // 32 x 8
  #pragma unroll
  for (int i = 0; i < 4; ++i)
    tile[ty + i*8][tx] = f2bf(in[(size_t)(k0 + ty + i*8) * N + n0 + tx]);
  __syncthreads();
  #pragma unroll
  for (int i = 0; i < 4; ++i)
    out[(size_t)(n0 + ty + i*8) * K + k0 + tx] = tile[tx][ty + i*8];
}

// base = x @ Wx + bx + bh  (fp32 into d_out)
__global__ __launch_bounds__(256) void k_xproj(
    const unsigned short* __restrict__ xbf,   // [16384][1024] bf16
    const unsigned short* __restrict__ wxt,   // [2048][1024]  bf16 (Wx^T)
    const float* __restrict__ bx,
    const float* __restrict__ bh,
    float* __restrict__ out)                  // [16384][2048] fp32
{
  int wave = threadIdx.x >> 6, lane = threadIdx.x & 63;
  int q = lane >> 4, r = lane & 15;
  int m0 = blockIdx.y * 64 + wave * 16;
  int n0 = blockIdx.x * 64;

  const unsigned short* arow = xbf + (size_t)(m0 + r) * NIN + q * 8;
  const unsigned short* brow = wxt + (size_t)(n0 + r) * NIN + q * 8;

  f32x4 acc[4] = {};
  #pragma unroll 2
  for (int kk = 0; kk < NIN; kk += 32){
    s16x8 a = *(const s16x8*)(arow + kk);
    #pragma unroll
    for (int j = 0; j < 4; ++j){
      s16x8 b = *(const s16x8*)(brow + (size_t)j * 16 * NIN + kk);
      acc[j] = __builtin_amdgcn_mfma_f32_16x16x32_bf16(a, b, acc[j], 0, 0, 0);
    }
  }
  #pragma unroll
  for (int j = 0; j < 4; ++j){
    int col = n0 + j * 16 + r;
    float bias = bx[col] + bh[col];
    #pragma unroll
    for (int i = 0; i < 4; ++i){
      int row = m0 + q * 4 + i;
      out[(size_t)row * NH + col] = acc[j][i] + bias;
    }
  }
}

// Persistent weight-stationary scan, v6 = v2 + plain write-back out stores.
// v2's proven structure (14.7us/step): 64 blocks x 8 waves, bf16 h ping-pong
// [64][2048], wave0 polls 64 padded flags -> agent acquire fence ->
// __syncthreads; hn sc0/sc1 stores drained by syncthreads' vmcnt(0) before the
// relaxed flag store.
// The ONLY change vs v2: epilogue `out` stores are plain cached write-back
// (one 16B store/thread) instead of 2x8B device-scope write-through atomics.
// v5 proved this is correct alongside the per-step acquire fence (dirty lines
// survive buffer_inv; consumers never read out during the scan; kernel-end
// release publishes dirty lines) and that it cuts WRITE_SIZE 336->~195 MB.
__global__ __launch_bounds__(SCAN_THREADS, 2) void k_scan_persist(
    unsigned short* __restrict__ hbuf,      // 2 x [64][2048] bf16 ping-pong (slot0 = h0)
    const unsigned short* __restrict__ wht, // [2048][2048] bf16 (Wh^T)
    float* __restrict__ out,                // [256][64][2048] fp32 (base in, tanh out)
    unsigned int* __restrict__ flags)       // 64 flags, stride 4 uints (16B), zeroed
{
  __shared__ float red[8][BATCH][36];

  const int tid = threadIdx.x;
  const int wave = tid >> 6, lane = tid & 63;
  const int q = lane >> 4, r = lane & 15;
  const int n0 = blockIdx.x * 32;
  const int kbase = wave * 256;

  // ---- preload Wh^T slice into registers (once): 2 n-tiles x 8 k-tiles ----
  s16x8 breg[2][8];
  #pragma unroll
  for (int kk = 0; kk < 8; ++kk)
    #pragma unroll
    for (int j = 0; j < 2; ++j)
      breg[j][kk] = *(const s16x8*)(wht + (size_t)(n0 + j*16 + r) * NH + kbase + kk*32 + q*8);

  const int crow = tid >> 3;        // 0..63  (epilogue mapping)
  const int ccol = (tid & 7) * 4;   // 0..28
  const size_t g = (size_t)crow * NH + n0 + ccol;

  // base for t=0 (plain load; only k_xproj has written these addresses)
  f32x4 base = *(const f32x4*)(out + g);

  for (int t = 0; t < S_LEN; ++t){
    const unsigned short* hc = hbuf + (size_t)(t & 1) * BATCH * NH;
    unsigned short* hn       = hbuf + (size_t)((t + 1) & 1) * BATCH * NH;
    float* outT = out + (size_t)t * BATCH * NH;

    // ---- wait: all blocks finished step t-1 ----
    if (t > 0){
      if (wave == 0){
        const unsigned int target = (unsigned int)t;
        const unsigned int* fp = flags + (lane << 2);   // 16B-strided flag per lane
        for (;;){
          unsigned int v = __hip_atomic_load(fp, __ATOMIC_RELAXED, __HIP_MEMORY_SCOPE_AGENT);
          if (__all((int)(v >= target))) break;
        }
        // make all blocks' device-scope h stores visible (inv L1/L2 clean lines)
        __builtin_amdgcn_fence(__ATOMIC_ACQUIRE, "agent");
      }
      __syncthreads();              // (C) release waves 1..7; orders their h loads
    }

    // ---- partial GEMM over this wave's k-range (K=256) ----
    f32x4 acc[4][2] = {};
    #pragma unroll 4
    for (int kk = 0; kk < 8; ++kk){
      s16x8 a[4];
      #pragma unroll
      for (int m = 0; m < 4; ++m)
        a[m] = *(const s16x8*)(hc + (size_t)(m*16 + r) * NH + kbase + kk*32 + q*8);
      #pragma unroll
      for (int m = 0; m < 4; ++m)
        #pragma unroll
        for (int j = 0; j < 2; ++j)
          acc[m][j] = __builtin_amdgcn_mfma_f32_16x16x32_bf16(a[m], breg[j][kk], acc[m][j], 0, 0, 0);
    }

    // ---- single-pass K-reduce staging: all 8 waves write partials ----
    #pragma unroll
    for (int m = 0; m < 4; ++m)
      #pragma unroll
      for (int j = 0; j < 2; ++j)
        #pragma unroll
        for (int i = 0; i < 4; ++i)
          red[wave][m*16 + q*4 + i][j*16 + r] = acc[m][j][i];
    __syncthreads();                // (A)

    // ---- epilogue: all 512 threads, 4 elems each ----
    {
      f32x4 s = *(const f32x4*)&red[0][crow][ccol];
      #pragma unroll
      for (int w = 1; w < 8; ++w)
        s += *(const f32x4*)&red[w][crow][ccol];
      f32x4 tv;
      #pragma unroll
      for (int i = 0; i < 4; ++i) tv[i] = tanhf(base[i] + s[i]);

      // out: PLAIN cached write-back store (full dirty lines, no EA amp;
      // no one reads out during the scan; kernel-end release publishes)
      *(f32x4*)(outT + g) = tv;

      // hn: device-scope write-through (consumers on other XCDs read it)
      union { unsigned short h[4]; unsigned long long u; } ph;
      #pragma unroll
      for (int i = 0; i < 4; ++i) ph.h[i] = f2bf(tv[i]);
      __hip_atomic_store((unsigned long long*)(hn + g), ph.u,
                         __ATOMIC_RELAXED, __HIP_MEMORY_SCOPE_AGENT);
    }

    __syncthreads();                // (B) vmcnt(0) drain => sc1 hn stores at MALL
    if (tid == 0)
      __hip_atomic_store(flags + ((unsigned)blockIdx.x << 2), (unsigned int)(t + 1),
                         __ATOMIC_RELAXED, __HIP_MEMORY_SCOPE_AGENT);

    // prefetch next step's base (plain; these addresses are written only by
    // k_xproj before the scan and by this block itself at step t+1)
    if (t + 1 < S_LEN)
      base = *(const f32x4*)(out + (size_t)(t + 1) * BATCH * NH + g);
  }
}

extern "C" void kernel_launch(void* const* d_in, const int* in_sizes, int n_in,
                              void* d_out, int out_size, void* d_ws, size_t ws_size,
                              hipStream_t stream){
  const float* x  = (const float*)d_in[0];
  const float* h0 = (const float*)d_in[1];
  const float* Wx = (const float*)d_in[2];
  const float* bx = (const float*)d_in[3];
  const float* Wh = (const float*)d_in[4];
  const float* bh = (const float*)d_in[5];
  float* out = (float*)d_out;

  char* ws = (char*)d_ws;
  unsigned short* xbf  = (unsigned short*)(ws);                               // 33,554,432 B
  unsigned short* wxt  = (unsigned short*)(ws + 33554432);                    //  4,194,304 B
  unsigned short* wht  = (unsigned short*)(ws + 33554432 + 4194304);          //  8,388,608 B
  unsigned short* hbuf = (unsigned short*)(ws + 33554432 + 4194304 + 8388608);//    524,288 B
  // flag array (64 x 16B) aliases xbf[0..512) — xbf is dead after k_xproj
  unsigned int* flags = (unsigned int*)ws;

  // 1) casts
  k_cast_bf16<<<dim3(16384), 256, 0, stream>>>(x,  xbf,  4194304);
  k_cast_bf16<<<dim3(128),   256, 0, stream>>>(h0, hbuf, 32768);
  // 2) weight transposes to [n][k] bf16
  k_transpose_bf16<<<dim3(NH/32, NIN/32), dim3(32, 8), 0, stream>>>(Wx, wxt, NIN, NH);
  k_transpose_bf16<<<dim3(NH/32, NH/32),  dim3(32, 8), 0, stream>>>(Wh, wht, NH, NH);
  // 3) base = x@Wx + bx + bh -> d_out
  k_xproj<<<dim3(NH/64, (S_LEN*BATCH)/64), 256, 0, stream>>>(xbf, wxt, bx, bh, out);
  // 4) zero flag array (xbf dead now), then persistent scan
  hipMemsetAsync(flags, 0, 1024, stream);
  {
    void* args[] = { (void*)&hbuf, (void*)&wht, (void*)&out, (void*)&flags };
    hipLaunchCooperativeKernel((const void*)k_scan_persist,
                               dim3(SCAN_BLOCKS), dim3(SCAN_THREADS), args, 0, stream);
  }
  // 5) hn = outputs[255]
  hipMemcpyAsync(out + (size_t)S_LEN * BATCH * NH,
                 out + (size_t)(S_LEN - 1) * BATCH * NH,
                 sizeof(float) * (size_t)BATCH * NH,
                 hipMemcpyDeviceToDevice, stream);
}

// Round 7
// 4161.289 us; speedup vs baseline: 2.2658x; 1.0148x over previous
//
#include <hip/hip_runtime.h>
#include <math.h>

#define S_LEN 256
#define BATCH 64
#define NIN   1024
#define NH    2048
#define SCAN_BLOCKS  64    // 32 cols each
#define SCAN_THREADS 512   // 8 waves, K-split 8x256
#define H_SLOTS 8          // h rotation depth; inv only at wrap

typedef short s16x8 __attribute__((ext_vector_type(8)));
typedef float f32x4 __attribute__((ext_vector_type(4)));
typedef unsigned short u16x4 __attribute__((ext_vector_type(4)));

__device__ inline unsigned short f2bf(float f){
  unsigned int u = __float_as_uint(f);
  u += 0x7fffu + ((u >> 16) & 1u);      // round-to-nearest-even
  return (unsigned short)(u >> 16);
}

__global__ void k_cast_bf16(const float* __restrict__ in,
                            unsigned short* __restrict__ out, int n4){
  int i = blockIdx.x * blockDim.x + threadIdx.x;
  if (i >= n4) return;
  float4 v = ((const float4*)in)[i];
  u16x4 o;
  o.x = f2bf(v.x); o.y = f2bf(v.y); o.z = f2bf(v.z); o.w = f2bf(v.w);
  ((u16x4*)out)[i] = o;
}

// out[n][k] = bf16(in[k][n]);  K,N multiples of 32
__global__ void k_transpose_bf16(const float* __restrict__ in,
                                 unsigned short* __restrict__ out, int K, int N){
  __shared__ unsigned short tile[32][33];
  int n0 = blockIdx.x * 32, k0 = blockIdx.y * 32;
  int tx = threadIdx.x, ty = threadIdx.y;   // 32 x 8
  #pragma unroll
  for (int i = 0; i < 4; ++i)
    tile[ty + i*8][tx] = f2bf(in[(size_t)(k0 + ty + i*8) * N + n0 + tx]);
  __syncthreads();
  #pragma unroll
  for (int i = 0; i < 4; ++i)
    out[(size_t)(n0 + ty + i*8) * K + k0 + tx] = tile[tx][ty + i*8];
}

// base = x @ Wx + bx + bh  (fp32 into d_out)
__global__ __launch_bounds__(256) void k_xproj(
    const unsigned short* __restrict__ xbf,   // [16384][1024] bf16
    const unsigned short* __restrict__ wxt,   // [2048][1024]  bf16 (Wx^T)
    const float* __restrict__ bx,
    const float* __restrict__ bh,
    float* __restrict__ out)                  // [16384][2048] fp32
{
  int wave = threadIdx.x >> 6, lane = threadIdx.x & 63;
  int q = lane >> 4, r = lane & 15;
  int m0 = blockIdx.y * 64 + wave * 16;
  int n0 = blockIdx.x * 64;

  const unsigned short* arow = xbf + (size_t)(m0 + r) * NIN + q * 8;
  const unsigned short* brow = wxt + (size_t)(n0 + r) * NIN + q * 8;

  f32x4 acc[4] = {};
  #pragma unroll 2
  for (int kk = 0; kk < NIN; kk += 32){
    s16x8 a = *(const s16x8*)(arow + kk);
    #pragma unroll
    for (int j = 0; j < 4; ++j){
      s16x8 b = *(const s16x8*)(brow + (size_t)j * 16 * NIN + kk);
      acc[j] = __builtin_amdgcn_mfma_f32_16x16x32_bf16(a, b, acc[j], 0, 0, 0);
    }
  }
  #pragma unroll
  for (int j = 0; j < 4; ++j){
    int col = n0 + j * 16 + r;
    float bias = bx[col] + bh[col];
    #pragma unroll
    for (int i = 0; i < 4; ++i){
      int row = m0 + q * 4 + i;
      out[(size_t)row * NH + col] = acc[j][i] + bias;
    }
  }
}

// Persistent weight-stationary scan, v7 = v6 + 8-slot h rotation.
// Theory: FETCH/WRITE are HBM-only; the h exchange lives in the MALL. The
// per-step cost driver is the per-block agent-acquire buffer_inv (8 per XCD
// per step, staggered) each wiping co-resident blocks' fresh h refills.
// Fix: rotate h over 8 slots (an address is reused only every 8 steps) and
// run the acquire fence ONLY at rotation wrap (t % 8 == 0). Each slot's
// cached lines see exactly one L1+L2 inv strictly between consecutive uses
// (cached at t, inv at the wrap in (t, t+8] before the re-read) => sound.
// hn stores stay sc0/sc1 write-through (update-if-present, no-allocate on
// miss => the store path never creates a stale line).
// Everything else is v6 verbatim (plain WB out stores, padded flags, wave0
// lane-parallel poll, syncthreads-drained release).
__global__ __launch_bounds__(SCAN_THREADS, 2) void k_scan_persist(
    unsigned short* __restrict__ hbuf,      // H_SLOTS x [64][2048] bf16 (slot0 = h0)
    const unsigned short* __restrict__ wht, // [2048][2048] bf16 (Wh^T)
    float* __restrict__ out,                // [256][64][2048] fp32 (base in, tanh out)
    unsigned int* __restrict__ flags)       // 64 flags, stride 4 uints (16B), zeroed
{
  __shared__ float red[8][BATCH][36];

  const int tid = threadIdx.x;
  const int wave = tid >> 6, lane = tid & 63;
  const int q = lane >> 4, r = lane & 15;
  const int n0 = blockIdx.x * 32;
  const int kbase = wave * 256;

  // ---- preload Wh^T slice into registers (once): 2 n-tiles x 8 k-tiles ----
  s16x8 breg[2][8];
  #pragma unroll
  for (int kk = 0; kk < 8; ++kk)
    #pragma unroll
    for (int j = 0; j < 2; ++j)
      breg[j][kk] = *(const s16x8*)(wht + (size_t)(n0 + j*16 + r) * NH + kbase + kk*32 + q*8);

  const int crow = tid >> 3;        // 0..63  (epilogue mapping)
  const int ccol = (tid & 7) * 4;   // 0..28
  const size_t g = (size_t)crow * NH + n0 + ccol;

  // base for t=0 (plain load; only k_xproj has written these addresses)
  f32x4 base = *(const f32x4*)(out + g);

  for (int t = 0; t < S_LEN; ++t){
    const unsigned short* hc = hbuf + (size_t)(t & (H_SLOTS-1)) * BATCH * NH;
    unsigned short* hn       = hbuf + (size_t)((t + 1) & (H_SLOTS-1)) * BATCH * NH;
    float* outT = out + (size_t)t * BATCH * NH;

    // ---- wait: all blocks finished step t-1 ----
    if (t > 0){
      if (wave == 0){
        const unsigned int target = (unsigned int)t;
        const unsigned int* fp = flags + (lane << 2);   // 16B-strided flag per lane
        for (;;){
          unsigned int v = __hip_atomic_load(fp, __ATOMIC_RELAXED, __HIP_MEMORY_SCOPE_AGENT);
          if (__all((int)(v >= target))) break;
        }
        // inv L1+L2 only at rotation wrap: clears lines cached 8 steps ago
        if ((t & (H_SLOTS-1)) == 0)
          __builtin_amdgcn_fence(__ATOMIC_ACQUIRE, "agent");
      }
      __syncthreads();              // (C) release waves 1..7; orders their h loads
    }

    // ---- partial GEMM over this wave's k-range (K=256) ----
    f32x4 acc[4][2] = {};
    #pragma unroll 4
    for (int kk = 0; kk < 8; ++kk){
      s16x8 a[4];
      #pragma unroll
      for (int m = 0; m < 4; ++m)
        a[m] = *(const s16x8*)(hc + (size_t)(m*16 + r) * NH + kbase + kk*32 + q*8);
      #pragma unroll
      for (int m = 0; m < 4; ++m)
        #pragma unroll
        for (int j = 0; j < 2; ++j)
          acc[m][j] = __builtin_amdgcn_mfma_f32_16x16x32_bf16(a[m], breg[j][kk], acc[m][j], 0, 0, 0);
    }

    // ---- single-pass K-reduce staging: all 8 waves write partials ----
    #pragma unroll
    for (int m = 0; m < 4; ++m)
      #pragma unroll
      for (int j = 0; j < 2; ++j)
        #pragma unroll
        for (int i = 0; i < 4; ++i)
          red[wave][m*16 + q*4 + i][j*16 + r] = acc[m][j][i];
    __syncthreads();                // (A)

    // ---- epilogue: all 512 threads, 4 elems each ----
    {
      f32x4 s = *(const f32x4*)&red[0][crow][ccol];
      #pragma unroll
      for (int w = 1; w < 8; ++w)
        s += *(const f32x4*)&red[w][crow][ccol];
      f32x4 tv;
      #pragma unroll
      for (int i = 0; i < 4; ++i) tv[i] = tanhf(base[i] + s[i]);

      // out: PLAIN cached write-back store (dirty lines survive buffer_inv;
      // nobody reads out during the scan; kernel-end release publishes)
      *(f32x4*)(outT + g) = tv;

      // hn: device-scope write-through (consumers on other XCDs read it)
      union { unsigned short h[4]; unsigned long long u; } ph;
      #pragma unroll
      for (int i = 0; i < 4; ++i) ph.h[i] = f2bf(tv[i]);
      __hip_atomic_store((unsigned long long*)(hn + g), ph.u,
                         __ATOMIC_RELAXED, __HIP_MEMORY_SCOPE_AGENT);
    }

    __syncthreads();                // (B) vmcnt(0) drain => sc1 hn stores at MALL
    if (tid == 0)
      __hip_atomic_store(flags + ((unsigned)blockIdx.x << 2), (unsigned int)(t + 1),
                         __ATOMIC_RELAXED, __HIP_MEMORY_SCOPE_AGENT);

    // prefetch next step's base (plain; these addresses are written only by
    // k_xproj before the scan and by this block itself at step t+1)
    if (t + 1 < S_LEN)
      base = *(const f32x4*)(out + (size_t)(t + 1) * BATCH * NH + g);
  }
}

extern "C" void kernel_launch(void* const* d_in, const int* in_sizes, int n_in,
                              void* d_out, int out_size, void* d_ws, size_t ws_size,
                              hipStream_t stream){
  const float* x  = (const float*)d_in[0];
  const float* h0 = (const float*)d_in[1];
  const float* Wx = (const float*)d_in[2];
  const float* bx = (const float*)d_in[3];
  const float* Wh = (const float*)d_in[4];
  const float* bh = (const float*)d_in[5];
  float* out = (float*)d_out;

  char* ws = (char*)d_ws;
  unsigned short* xbf  = (unsigned short*)(ws);                               // 33,554,432 B
  unsigned short* wxt  = (unsigned short*)(ws + 33554432);                    //  4,194,304 B
  unsigned short* wht  = (unsigned short*)(ws + 33554432 + 4194304);          //  8,388,608 B
  // flags (64 x 16B) at ws[0..1KB); hbuf (8 slots x 256KB = 2MB) at ws+4096.
  // Both alias xbf, which is dead after k_xproj; h0 is cast into slot 0 only
  // after k_xproj completes (stream order). hbuf does NOT overlap wxt/wht.
  unsigned int* flags = (unsigned int*)ws;
  unsigned short* hbuf = (unsigned short*)(ws + 4096);

  // 1) cast x to bf16
  k_cast_bf16<<<dim3(16384), 256, 0, stream>>>(x, xbf, 4194304);
  // 2) weight transposes to [n][k] bf16
  k_transpose_bf16<<<dim3(NH/32, NIN/32), dim3(32, 8), 0, stream>>>(Wx, wxt, NIN, NH);
  k_transpose_bf16<<<dim3(NH/32, NH/32),  dim3(32, 8), 0, stream>>>(Wh, wht, NH, NH);
  // 3) base = x@Wx + bx + bh -> d_out
  k_xproj<<<dim3(NH/64, (S_LEN*BATCH)/64), 256, 0, stream>>>(xbf, wxt, bx, bh, out);
  // 4) xbf now dead: cast h0 into hbuf slot 0, zero flags, run scan
  k_cast_bf16<<<dim3(128), 256, 0, stream>>>(h0, hbuf, 32768);
  hipMemsetAsync(flags, 0, 1024, stream);
  {
    void* args[] = { (void*)&hbuf, (void*)&wht, (void*)&out, (void*)&flags };
    hipLaunchCooperativeKernel((const void*)k_scan_persist,
                               dim3(SCAN_BLOCKS), dim3(SCAN_THREADS), args, 0, stream);
  }
  // 5) hn = outputs[255]
  hipMemcpyAsync(out + (size_t)S_LEN * BATCH * NH,
                 out + (size_t)(S_LEN - 1) * BATCH * NH,
                 sizeof(float) * (size_t)BATCH * NH,
                 hipMemcpyDeviceToDevice, stream);
}

// Round 9
// 3249.577 us; speedup vs baseline: 2.9016x; 1.2806x over previous
//
#include <hip/hip_runtime.h>
#include <math.h>

#define S_LEN 256
#define BATCH 64
#define NIN   1024
#define NH    2048
#define SCAN_BLOCKS  64    // 32 cols each
#define SCAN_THREADS 512   // 8 waves, K-split 8x256
#define H_SLOTS 8          // h rotation depth; inv only at wrap

typedef short s16x8 __attribute__((ext_vector_type(8)));
typedef float f32x4 __attribute__((ext_vector_type(4)));
typedef unsigned short u16x4 __attribute__((ext_vector_type(4)));

__device__ inline unsigned short f2bf(float f){
  unsigned int u = __float_as_uint(f);
  u += 0x7fffu + ((u >> 16) & 1u);      // round-to-nearest-even
  return (unsigned short)(u >> 16);
}

__global__ void k_cast_bf16(const float* __restrict__ in,
                            unsigned short* __restrict__ out, int n4){
  int i = blockIdx.x * blockDim.x + threadIdx.x;
  if (i >= n4) return;
  float4 v = ((const float4*)in)[i];
  u16x4 o;
  o.x = f2bf(v.x); o.y = f2bf(v.y); o.z = f2bf(v.z); o.w = f2bf(v.w);
  ((u16x4*)out)[i] = o;
}

// out[n][k] = bf16(in[k][n]);  K,N multiples of 32
__global__ void k_transpose_bf16(const float* __restrict__ in,
                                 unsigned short* __restrict__ out, int K, int N){
  __shared__ unsigned short tile[32][33];
  int n0 = blockIdx.x * 32, k0 = blockIdx.y * 32;
  int tx = threadIdx.x, ty = threadIdx.y;   // 32 x 8
  #pragma unroll
  for (int i = 0; i < 4; ++i)
    tile[ty + i*8][tx] = f2bf(in[(size_t)(k0 + ty + i*8) * N + n0 + tx]);
  __syncthreads();
  #pragma unroll
  for (int i = 0; i < 4; ++i)
    out[(size_t)(n0 + ty + i*8) * K + k0 + tx] = tile[tx][ty + i*8];
}

// base = x @ Wx + bx + bh  (fp32 into d_out)
__global__ __launch_bounds__(256) void k_xproj(
    const unsigned short* __restrict__ xbf,   // [16384][1024] bf16
    const unsigned short* __restrict__ wxt,   // [2048][1024]  bf16 (Wx^T)
    const float* __restrict__ bx,
    const float* __restrict__ bh,
    float* __restrict__ out)                  // [16384][2048] fp32
{
  int wave = threadIdx.x >> 6, lane = threadIdx.x & 63;
  int q = lane >> 4, r = lane & 15;
  int m0 = blockIdx.y * 64 + wave * 16;
  int n0 = blockIdx.x * 64;

  const unsigned short* arow = xbf + (size_t)(m0 + r) * NIN + q * 8;
  const unsigned short* brow = wxt + (size_t)(n0 + r) * NIN + q * 8;

  f32x4 acc[4] = {};
  #pragma unroll 2
  for (int kk = 0; kk < NIN; kk += 32){
    s16x8 a = *(const s16x8*)(arow + kk);
    #pragma unroll
    for (int j = 0; j < 4; ++j){
      s16x8 b = *(const s16x8*)(brow + (size_t)j * 16 * NIN + kk);
      acc[j] = __builtin_amdgcn_mfma_f32_16x16x32_bf16(a, b, acc[j], 0, 0, 0);
    }
  }
  #pragma unroll
  for (int j = 0; j < 4; ++j){
    int col = n0 + j * 16 + r;
    float bias = bx[col] + bh[col];
    #pragma unroll
    for (int i = 0; i < 4; ++i){
      int row = m0 + q * 4 + i;
      out[(size_t)row * NH + col] = acc[j][i] + bias;
    }
  }
}

// Persistent weight-stationary scan, v9 = v7 (proven sync skeleton, passed 2x)
// + full h-prefetch ONLY (sync-neutral: same addresses/values, reordered).
// v8's per-wave waits are DROPPED — they produced a single-row numerical
// corruption (timing-window race); one semantic change per probe.
// Prefetch: all 32 h fragment loads issued back-to-back into a[8][4] before
// any MFMA -> ~32 outstanding misses/wave (2x v7's unroll-4 structure),
// attacking the MALL-latency-bound h broadcast identified in round 7.
__global__ __launch_bounds__(SCAN_THREADS, 2) void k_scan_persist(
    unsigned short* __restrict__ hbuf,      // H_SLOTS x [64][2048] bf16 (slot0 = h0)
    const unsigned short* __restrict__ wht, // [2048][2048] bf16 (Wh^T)
    float* __restrict__ out,                // [256][64][2048] fp32 (base in, tanh out)
    unsigned int* __restrict__ flags)       // 64 flags, stride 4 uints (16B), zeroed
{
  __shared__ float red[8][BATCH][36];

  const int tid = threadIdx.x;
  const int wave = tid >> 6, lane = tid & 63;
  const int q = lane >> 4, r = lane & 15;
  const int n0 = blockIdx.x * 32;
  const int kbase = wave * 256;

  // ---- preload Wh^T slice into registers (once): 2 n-tiles x 8 k-tiles ----
  s16x8 breg[2][8];
  #pragma unroll
  for (int kk = 0; kk < 8; ++kk)
    #pragma unroll
    for (int j = 0; j < 2; ++j)
      breg[j][kk] = *(const s16x8*)(wht + (size_t)(n0 + j*16 + r) * NH + kbase + kk*32 + q*8);

  const int crow = tid >> 3;        // 0..63  (epilogue mapping)
  const int ccol = (tid & 7) * 4;   // 0..28
  const size_t g = (size_t)crow * NH + n0 + ccol;

  // base for t=0 (plain load; only k_xproj has written these addresses)
  f32x4 base = *(const f32x4*)(out + g);

  for (int t = 0; t < S_LEN; ++t){
    const unsigned short* hc = hbuf + (size_t)(t & (H_SLOTS-1)) * BATCH * NH;
    unsigned short* hn       = hbuf + (size_t)((t + 1) & (H_SLOTS-1)) * BATCH * NH;
    float* outT = out + (size_t)t * BATCH * NH;

    // ---- wait: all blocks finished step t-1 (v7 skeleton, proven) ----
    if (t > 0){
      if (wave == 0){
        const unsigned int target = (unsigned int)t;
        const unsigned int* fp = flags + (lane << 2);   // 16B-strided flag per lane
        for (;;){
          unsigned int v = __hip_atomic_load(fp, __ATOMIC_RELAXED, __HIP_MEMORY_SCOPE_AGENT);
          if (__all((int)(v >= target))) break;
        }
        // inv L1+L2 only at rotation wrap: clears lines cached 8 steps ago
        if ((t & (H_SLOTS-1)) == 0)
          __builtin_amdgcn_fence(__ATOMIC_ACQUIRE, "agent");
      }
      __syncthreads();              // (C) release waves 1..7; orders their h loads
    }

    // ---- full prefetch: all 32 h fragment loads in flight, then MFMA ----
    s16x8 a[8][4];
    #pragma unroll
    for (int kk = 0; kk < 8; ++kk)
      #pragma unroll
      for (int m = 0; m < 4; ++m)
        a[kk][m] = *(const s16x8*)(hc + (size_t)(m*16 + r) * NH + kbase + kk*32 + q*8);

    f32x4 acc[4][2] = {};
    #pragma unroll
    for (int kk = 0; kk < 8; ++kk)
      #pragma unroll
      for (int m = 0; m < 4; ++m)
        #pragma unroll
        for (int j = 0; j < 2; ++j)
          acc[m][j] = __builtin_amdgcn_mfma_f32_16x16x32_bf16(a[kk][m], breg[j][kk], acc[m][j], 0, 0, 0);

    // ---- single-pass K-reduce staging: all 8 waves write partials ----
    #pragma unroll
    for (int m = 0; m < 4; ++m)
      #pragma unroll
      for (int j = 0; j < 2; ++j)
        #pragma unroll
        for (int i = 0; i < 4; ++i)
          red[wave][m*16 + q*4 + i][j*16 + r] = acc[m][j][i];
    __syncthreads();                // (A)

    // ---- epilogue: all 512 threads, 4 elems each ----
    {
      f32x4 s = *(const f32x4*)&red[0][crow][ccol];
      #pragma unroll
      for (int w = 1; w < 8; ++w)
        s += *(const f32x4*)&red[w][crow][ccol];
      f32x4 tv;
      #pragma unroll
      for (int i = 0; i < 4; ++i) tv[i] = tanhf(base[i] + s[i]);

      // out: PLAIN cached write-back store (nobody reads out during the scan;
      // kernel-end release publishes dirty lines)
      *(f32x4*)(outT + g) = tv;

      // hn: device-scope write-through (consumers on other XCDs read it)
      union { unsigned short h[4]; unsigned long long u; } ph;
      #pragma unroll
      for (int i = 0; i < 4; ++i) ph.h[i] = f2bf(tv[i]);
      __hip_atomic_store((unsigned long long*)(hn + g), ph.u,
                         __ATOMIC_RELAXED, __HIP_MEMORY_SCOPE_AGENT);
    }

    __syncthreads();                // (B) vmcnt(0) drain => sc1 hn stores at MALL
    if (tid == 0)
      __hip_atomic_store(flags + ((unsigned)blockIdx.x << 2), (unsigned int)(t + 1),
                         __ATOMIC_RELAXED, __HIP_MEMORY_SCOPE_AGENT);

    // prefetch next step's base (plain; written only by k_xproj and later by
    // this block itself -> L1-coherent for its only reader)
    if (t + 1 < S_LEN)
      base = *(const f32x4*)(out + (size_t)(t + 1) * BATCH * NH + g);
  }
}

extern "C" void kernel_launch(void* const* d_in, const int* in_sizes, int n_in,
                              void* d_out, int out_size, void* d_ws, size_t ws_size,
                              hipStream_t stream){
  const float* x  = (const float*)d_in[0];
  const float* h0 = (const float*)d_in[1];
  const float* Wx = (const float*)d_in[2];
  const float* bx = (const float*)d_in[3];
  const float* Wh = (const float*)d_in[4];
  const float* bh = (const float*)d_in[5];
  float* out = (float*)d_out;

  char* ws = (char*)d_ws;
  unsigned short* xbf  = (unsigned short*)(ws);                               // 33,554,432 B
  unsigned short* wxt  = (unsigned short*)(ws + 33554432);                    //  4,194,304 B
  unsigned short* wht  = (unsigned short*)(ws + 33554432 + 4194304);          //  8,388,608 B
  // flags (64 x 16B) at ws[0..1KB); hbuf (8 slots x 256KB = 2MB) at ws+4096.
  // Both alias xbf, which is dead after k_xproj; h0 is cast into slot 0 only
  // after k_xproj completes (stream order). hbuf does NOT overlap wxt/wht.
  unsigned int* flags = (unsigned int*)ws;
  unsigned short* hbuf = (unsigned short*)(ws + 4096);

  // 1) cast x to bf16
  k_cast_bf16<<<dim3(16384), 256, 0, stream>>>(x, xbf, 4194304);
  // 2) weight transposes to [n][k] bf16
  k_transpose_bf16<<<dim3(NH/32, NIN/32), dim3(32, 8), 0, stream>>>(Wx, wxt, NIN, NH);
  k_transpose_bf16<<<dim3(NH/32, NH/32),  dim3(32, 8), 0, stream>>>(Wh, wht, NH, NH);
  // 3) base = x@Wx + bx + bh -> d_out
  k_xproj<<<dim3(NH/64, (S_LEN*BATCH)/64), 256, 0, stream>>>(xbf, wxt, bx, bh, out);
  // 4) xbf now dead: cast h0 into hbuf slot 0, zero flags, run scan
  k_cast_bf16<<<dim3(128), 256, 0, stream>>>(h0, hbuf, 32768);
  hipMemsetAsync(flags, 0, 1024, stream);
  {
    void* args[] = { (void*)&hbuf, (void*)&wht, (void*)&out, (void*)&flags };
    hipLaunchCooperativeKernel((const void*)k_scan_persist,
                               dim3(SCAN_BLOCKS), dim3(SCAN_THREADS), args, 0, stream);
  }
  // 5) hn = outputs[255]
  hipMemcpyAsync(out + (size_t)S_LEN * BATCH * NH,
                 out + (size_t)(S_LEN - 1) * BATCH * NH,
                 sizeof(float) * (size_t)BATCH * NH,
                 hipMemcpyDeviceToDevice, stream);
}